// Round 3
// baseline (472.631 us; speedup 1.0000x reference)
//
#include <hip/hip_runtime.h>
#include <hip/hip_bf16.h>
#include <cstdint>
#include <cstddef>

#define BB 8
#define SS 1024
#define DDIM 768
#define FFF 3072
#define EE 8

typedef __attribute__((ext_vector_type(8))) short short8;
typedef __attribute__((ext_vector_type(4))) float f32x4;
typedef __attribute__((ext_vector_type(4))) unsigned short us4;

__device__ __forceinline__ unsigned short f2bf(float f) {
  unsigned u = __float_as_uint(f);
  u += 0x7FFFu + ((u >> 16) & 1u);
  return (unsigned short)(u >> 16);
}

__device__ __forceinline__ void async_ld16(const void* g, void* l) {
  __builtin_amdgcn_global_load_lds(
      (const __attribute__((address_space(1))) void*)g,
      (__attribute__((address_space(3))) void*)l, 16, 0, 0);
}

// ---------------- fused prep: tcast W1 | tcast W2 | cast x | pooled ----------------
__global__ __launch_bounds__(256) void prep_kernel(
    const float* __restrict__ W1, const float* __restrict__ W2,
    const float* __restrict__ x,
    unsigned short* __restrict__ w1t, unsigned short* __restrict__ w2t,
    unsigned short* __restrict__ xb, float* __restrict__ pooled) {
  __shared__ unsigned short tile[64 * 66 + 32];
  int blk = blockIdx.x;
  int t = threadIdx.x;
  if (blk < 9216) {
    const float* src; unsigned short* dst; int R, C, r0, c0;
    if (blk < 4608) {
      int e = blk / 576, rem = blk % 576;           // 12 r-tiles x 48 c-tiles
      r0 = (rem / 48) * 64; c0 = (rem % 48) * 64;
      src = W1 + (size_t)e * DDIM * FFF; dst = w1t + (size_t)e * FFF * DDIM;
      R = DDIM; C = FFF;
    } else {
      int b2 = blk - 4608;
      int e = b2 / 576, rem = b2 % 576;             // 48 r-tiles x 12 c-tiles
      r0 = (rem / 12) * 64; c0 = (rem % 12) * 64;
      src = W2 + (size_t)e * FFF * DDIM; dst = w2t + (size_t)e * DDIM * FFF;
      R = FFF; C = DDIM;
    }
    int row = t >> 4, c4 = (t & 15) * 4;
#pragma unroll
    for (int it = 0; it < 4; it++) {
      int r = row + it * 16;
      float4 v = *(const float4*)&src[(size_t)(r0 + r) * C + c0 + c4];
      us4 u; u[0] = f2bf(v.x); u[1] = f2bf(v.y); u[2] = f2bf(v.z); u[3] = f2bf(v.w);
      *(us4*)&tile[r * 66 + c4] = u;
    }
    __syncthreads();
    int seg = (t & 7) * 8;
#pragma unroll
    for (int it = 0; it < 2; it++) {
      int crow = it * 32 + (t >> 3);
      short8 u;
#pragma unroll
      for (int j = 0; j < 8; j++) u[j] = (short)tile[(seg + j) * 66 + crow];
      *(short8*)&dst[(size_t)(c0 + crow) * R + r0 + seg] = u;
    }
  } else if (blk < 12288) {
    size_t i = ((size_t)(blk - 9216) * 256 + t) * 8;
    float4 a = *(const float4*)&x[i];
    float4 b = *(const float4*)&x[i + 4];
    short8 u;
    u[0] = f2bf(a.x); u[1] = f2bf(a.y); u[2] = f2bf(a.z); u[3] = f2bf(a.w);
    u[4] = f2bf(b.x); u[5] = f2bf(b.y); u[6] = f2bf(b.z); u[7] = f2bf(b.w);
    *(short8*)&xb[i] = u;
  } else {
    float* red = (float*)tile;
    int blk2 = blk - 12288;
    int b = blk2 / 24, d0 = (blk2 % 24) * 32;
    int dl = t & 31, sg = t >> 5;
    const float* p = x + ((size_t)b * SS + sg) * DDIM + d0 + dl;
    float s = 0.f;
#pragma unroll 4
    for (int i = 0; i < SS / 8; i++) s += p[(size_t)i * 8 * DDIM];
    red[t] = s;
    __syncthreads();
    if (t < 32) {
      float acc = red[t];
#pragma unroll
      for (int g = 1; g < 8; g++) acc += red[g * 32 + t];
      pooled[b * DDIM + d0 + t] = acc * (1.f / SS);
    }
  }
}

// ---------------- router ----------------
__global__ void router_kernel(const float* __restrict__ pooled,
                              const float* __restrict__ text,
                              const float* __restrict__ rw,
                              const float* __restrict__ rb,
                              float* __restrict__ probs_out,
                              int* __restrict__ topi,
                              float* __restrict__ topv) {
  __shared__ float lg[BB * EE];
  int t = threadIdx.x;
  int be = t >> 4, part = t & 15;
  int b = be >> 3, e = be & 7;
  const float* pb = pooled + b * DDIM;
  const float* tb = text + b * DDIM;
  float acc = 0.f;
  int i0 = part * 96;
  for (int i = i0; i < i0 + 96; i++) {
    float f = (i < DDIM) ? pb[i] : tb[i - DDIM];
    acc += f * rw[i * EE + e];
  }
#pragma unroll
  for (int o = 8; o >= 1; o >>= 1) acc += __shfl_xor(acc, o);
  if (part == 0) lg[be] = acc + rb[e];
  __syncthreads();
  if (t < BB) {
    float p[EE];
    float mx = -1e30f;
    for (int e2 = 0; e2 < EE; e2++) { p[e2] = lg[t * EE + e2]; mx = fmaxf(mx, p[e2]); }
    float s = 0.f;
    for (int e2 = 0; e2 < EE; e2++) { p[e2] = expf(p[e2] - mx); s += p[e2]; }
    float inv = 1.f / s;
    for (int e2 = 0; e2 < EE; e2++) { p[e2] *= inv; probs_out[t * EE + e2] = p[e2]; }
    int j0 = 0; float v0 = p[0];
    for (int e2 = 1; e2 < EE; e2++) if (p[e2] > v0) { v0 = p[e2]; j0 = e2; }
    int j1 = -1; float v1 = -1e30f;
    for (int e2 = 0; e2 < EE; e2++) if (e2 != j0 && p[e2] > v1) { v1 = p[e2]; j1 = e2; }
    topi[t * 2] = j0; topi[t * 2 + 1] = j1;
    topv[t * 2] = v0; topv[t * 2 + 1] = v1;
  }
}

// ============ 8-phase lockstep building blocks ============
#define A_READS(pp, so_)                                                        \
    short8 a0k0 = *(const short8*)&sm[(so_) + aoff + (2 * (pp)) * 1024 + ch0];  \
    short8 a0k1 = *(const short8*)&sm[(so_) + aoff + (2 * (pp)) * 1024 + ch1];  \
    short8 a1k0 = *(const short8*)&sm[(so_) + aoff + (2 * (pp) + 1) * 1024 + ch0]; \
    short8 a1k1 = *(const short8*)&sm[(so_) + aoff + (2 * (pp) + 1) * 1024 + ch1];

#define RDB(so_)                                                             \
    _Pragma("unroll") for (int j = 0; j < 4; j++) {                          \
      bf[j][0] = *(const short8*)&sm[(so_) + boff + j * 1024 + ch0];         \
      bf[j][1] = *(const short8*)&sm[(so_) + boff + j * 1024 + ch1];         \
    }

#define ENTRY_BAR                                          \
    asm volatile("" ::: "memory");                         \
    __builtin_amdgcn_s_barrier();                          \
    asm volatile("s_waitcnt lgkmcnt(0)" ::: "memory");     \
    __builtin_amdgcn_sched_barrier(0);

#define CLOSE_BAR                                          \
    asm volatile("" ::: "memory");                         \
    __builtin_amdgcn_s_barrier();

#define LGK8 asm volatile("s_waitcnt lgkmcnt(8)" ::: "memory");

#define MFMA16(pp)                                                                   \
    __builtin_amdgcn_s_setprio(1);                                                   \
    _Pragma("unroll") for (int j = 0; j < 4; j++) {                                  \
      acc[2 * (pp)][j] = __builtin_amdgcn_mfma_f32_16x16x32_bf16(a0k0, bf[j][0], acc[2 * (pp)][j], 0, 0, 0); \
      acc[2 * (pp)][j] = __builtin_amdgcn_mfma_f32_16x16x32_bf16(a0k1, bf[j][1], acc[2 * (pp)][j], 0, 0, 0); \
      acc[2 * (pp) + 1][j] = __builtin_amdgcn_mfma_f32_16x16x32_bf16(a1k0, bf[j][0], acc[2 * (pp) + 1][j], 0, 0, 0); \
      acc[2 * (pp) + 1][j] = __builtin_amdgcn_mfma_f32_16x16x32_bf16(a1k1, bf[j][1], acc[2 * (pp) + 1][j], 0, 0, 0); \
    }                                                                                \
    __builtin_amdgcn_s_setprio(0);                                                   \
    __builtin_amdgcn_sched_barrier(0);

// ---------------- GEMM1: persistent 256 blocks x 3 M-tiles of 256x256, K=768 ----------------
// LDS stage (ush): A units @0,4096,8192,12288; B units @16384..28672; stage1 +32768.
// 8-phase/iter (2 K-tiles). Loads 2/phase. Waits: vmcnt(6) end-p3 & end-p7; last iter vmcnt(0).
__global__ __launch_bounds__(512, 2) void gemm1_pipe(
    const unsigned short* __restrict__ w1t,
    const unsigned short* __restrict__ xb,
    const float* __restrict__ b1,
    const int* __restrict__ topi,
    const float* __restrict__ topv,
    unsigned short* __restrict__ h) {
  int wg = (blockIdx.x & 7) * 32 + (blockIdx.x >> 3);  // XCD swizzle (256%8==0)
  int pair = wg >> 4;
  int sub = wg & 15;
  int Mg = sub >> 2;
  int N0 = (sub & 3) * 256;
  int e = topi[pair];
  float tv = topv[pair];
  const unsigned short* A = w1t + (size_t)e * DDIM * FFF + (size_t)Mg * 768 * DDIM;
  const unsigned short* B = xb + (size_t)(pair >> 1) * SS * DDIM + (size_t)N0 * DDIM;

  __shared__ unsigned short sm[65536 + 1536];
  float* biasLds = (float*)&sm[65536];
  int t = threadIdx.x;
  int lane = t & 63, wave = t >> 6;
  int wm = wave >> 2, wn = wave & 3;

  if (t < 192) {
    float4 bv = *(const float4*)&b1[e * FFF + Mg * 768 + t * 4];
    *(float4*)&biasLds[t * 4] = bv;
  }
  __syncthreads();  // clean vm/lgkm ledger before prologue

  int sr = t >> 3, c4 = t & 7;
  int gch = (c4 ^ (sr & 7)) * 8;  // pre-swizzled global source (T2)
  const unsigned short* gA = A + (size_t)sr * DDIM + gch;
  const unsigned short* gB = B + (size_t)sr * DDIM + gch;
  unsigned short* lds_t = sm + t * 8;

#define G1(ptr, rofs, ldso) async_ld16((ptr) + (size_t)(rofs) * DDIM, lds_t + (ldso))

  // prologue: tile0 full (8), tile1 partial (B x4, A a0,a2)
  G1(gA, 0, 0); G1(gA, 64, 4096); G1(gA, 128, 8192); G1(gA, 192, 12288);
  G1(gB, 0, 16384); G1(gB, 64, 20480); G1(gB, 128, 24576); G1(gB, 192, 28672);
  G1(gB + 64, 0, 32768 + 16384); G1(gB + 64, 64, 32768 + 20480);
  G1(gB + 64, 128, 32768 + 24576); G1(gB + 64, 192, 32768 + 28672);
  G1(gA + 64, 0, 32768 + 0); G1(gA + 64, 128, 32768 + 8192);
  asm volatile("s_waitcnt vmcnt(6)" ::: "memory");
  __builtin_amdgcn_s_barrier();

  f32x4 acc[8][4];
#pragma unroll
  for (int i = 0; i < 8; i++)
#pragma unroll
    for (int j = 0; j < 4; j++) acc[i][j] = (f32x4){0.f, 0.f, 0.f, 0.f};

  int l15 = lane & 15, lg = lane >> 4, lx = lane & 7;
  int ch0 = (lg ^ lx) * 8;
  int ch1 = ((4 + lg) ^ lx) * 8;
  int aoff = wm * 8192 + l15 * 64;
  int boff = 16384 + wn * 4096 + l15 * 64;

#pragma unroll 1
  for (int mi = 0; mi < 3; mi++) {
#pragma unroll 1
    for (int j2 = 0; j2 < 6; j2++) {
      bool last = (mi == 2) && (j2 == 5);
      int mi2 = (j2 == 5) ? mi + 1 : mi;
      int kk2 = (j2 == 5) ? 0 : (2 * j2 + 2) * 64;
      int kk3 = (j2 == 5) ? 64 : (2 * j2 + 3) * 64;
      const unsigned short* aV1 = gA + (size_t)mi * (256 * DDIM) + (2 * j2 + 1) * 64;
      const unsigned short* aT2 = gA + (size_t)mi2 * (256 * DDIM) + kk2;
      const unsigned short* aT3 = gA + (size_t)mi2 * (256 * DDIM) + kk3;
      const unsigned short* bT2 = gB + kk2;
      const unsigned short* bT3 = gB + kk3;
      {  // ---- stage 0 group (K-tile v0) ----
        short8 bf[4][2];
        {  // p0
          A_READS(0, 0); RDB(0);
          G1(aV1, 64, 32768 + 4096); G1(aV1, 192, 32768 + 12288);
          LGK8; ENTRY_BAR; MFMA16(0); CLOSE_BAR;
        }
        {  // p1
          A_READS(1, 0);
          if (!last) { G1(bT2, 0, 16384); G1(bT2, 64, 20480); }
          ENTRY_BAR; MFMA16(1); CLOSE_BAR;
        }
        {  // p2
          A_READS(2, 0);
          if (!last) { G1(bT2, 128, 24576); G1(bT2, 192, 28672); }
          ENTRY_BAR; MFMA16(2); CLOSE_BAR;
        }
        {  // p3 (+ stage-switch wait)
          A_READS(3, 0);
          if (!last) { G1(aT2, 0, 0); G1(aT2, 128, 8192); }
          ENTRY_BAR; MFMA16(3);
          if (last) asm volatile("s_waitcnt vmcnt(0)" ::: "memory");
          else      asm volatile("s_waitcnt vmcnt(6)" ::: "memory");
          CLOSE_BAR;
        }
      }
      {  // ---- stage 1 group (K-tile v1) ----
        short8 bf[4][2];
        {  // p4
          A_READS(0, 32768); RDB(32768);
          if (!last) { G1(aT2, 64, 4096); G1(aT2, 192, 12288); }
          LGK8; ENTRY_BAR; MFMA16(0); CLOSE_BAR;
        }
        {  // p5
          A_READS(1, 32768);
          if (!last) { G1(bT3, 0, 32768 + 16384); G1(bT3, 64, 32768 + 20480); }
          ENTRY_BAR; MFMA16(1); CLOSE_BAR;
        }
        {  // p6
          A_READS(2, 32768);
          if (!last) { G1(bT3, 128, 32768 + 24576); G1(bT3, 192, 32768 + 28672); }
          ENTRY_BAR; MFMA16(2); CLOSE_BAR;
        }
        {  // p7 (+ stage-switch wait)
          A_READS(3, 32768);
          if (!last) { G1(aT3, 0, 32768 + 0); G1(aT3, 128, 32768 + 8192); }
          ENTRY_BAR; MFMA16(3);
          if (!last) asm volatile("s_waitcnt vmcnt(6)" ::: "memory");
          CLOSE_BAR;
        }
      }
      if (j2 == 5) {
        // ---- epilogue for M-tile mi (stores sit AFTER the protected wait) ----
        int fb_loc = mi * 256 + wm * 128 + lg * 4;
        int fb0 = Mg * 768 + fb_loc;
        int sb0 = N0 + wn * 64 + l15;
        unsigned short* ho = h + (size_t)pair * SS * FFF;
        f32x4 bias[8];
#pragma unroll
        for (int i = 0; i < 8; i++)
          bias[i] = *(const f32x4*)&biasLds[fb_loc + i * 16];
#pragma unroll
        for (int j = 0; j < 4; j++) {
          int s = sb0 + j * 16;
#pragma unroll
          for (int i = 0; i < 8; i++) {
            us4 u;
#pragma unroll
            for (int r = 0; r < 4; r++) {
              float v = acc[i][j][r] + bias[i][r];
              float v2 = v * v;
              float u2 = v * (1.5957691216057308f + 0.07135481627f * v2);
              float ex = __expf(-u2);
              float g = v / (1.f + ex);
              u[r] = f2bf(g * tv);
            }
            *(us4*)&ho[(size_t)s * FFF + fb0 + i * 16] = u;
          }
        }
#pragma unroll
        for (int i = 0; i < 8; i++)
#pragma unroll
          for (int j = 0; j < 4; j++) acc[i][j] = (f32x4){0.f, 0.f, 0.f, 0.f};
        asm volatile("" ::: "memory");
      }
    }
  }
#undef G1
}

// ---------------- GEMM2: 192x256 tiles, 256 blocks, K=3072, 6-phase lockstep ----------------
// LDS stage (ush): A units @0,4096,8192; B units @12288..24576; stage1 +28672.
// Waits: vmcnt(5) end-p2 & end-p5; last iter vmcnt(0)/skip.
__global__ __launch_bounds__(512, 2) void gemm2_pipe(
    const unsigned short* __restrict__ w2t,
    const unsigned short* __restrict__ h,
    const int* __restrict__ topi,
    float* __restrict__ y) {
  int wg = (blockIdx.x & 7) * 32 + (blockIdx.x >> 3);  // XCD swizzle
  int pair = wg >> 4;
  int sub = wg & 15;
  int M0 = (sub >> 2) * 192;
  int N0 = (sub & 3) * 256;
  int e = topi[pair];
  const unsigned short* A = w2t + (size_t)e * DDIM * FFF;
  const unsigned short* Bm = h + (size_t)pair * SS * FFF;

  __shared__ unsigned short sm[57344];
  int t = threadIdx.x;
  int lane = t & 63, wave = t >> 6;
  int wm = wave >> 2, wn = wave & 3;

  int sr = t >> 3, c4 = t & 7;
  int gch = (c4 ^ (sr & 7)) * 8;
  const unsigned short* gA = A + (size_t)(M0 + sr) * FFF + gch;
  const unsigned short* gB = Bm + (size_t)(N0 + sr) * FFF + gch;
  unsigned short* lds_t = sm + t * 8;

#define G2(ptr, rofs, ldso) async_ld16((ptr) + (size_t)(rofs) * FFF, lds_t + (ldso))

  // prologue: tile0 full (7), tile1 partial (B x4, a0)
  G2(gA, 0, 0); G2(gA, 64, 4096); G2(gA, 128, 8192);
  G2(gB, 0, 12288); G2(gB, 64, 16384); G2(gB, 128, 20480); G2(gB, 192, 24576);
  G2(gB + 64, 0, 28672 + 12288); G2(gB + 64, 64, 28672 + 16384);
  G2(gB + 64, 128, 28672 + 20480); G2(gB + 64, 192, 28672 + 24576);
  G2(gA + 64, 0, 28672 + 0);
  asm volatile("s_waitcnt vmcnt(5)" ::: "memory");
  __builtin_amdgcn_s_barrier();

  f32x4 acc[6][4];
#pragma unroll
  for (int i = 0; i < 6; i++)
#pragma unroll
    for (int j = 0; j < 4; j++) acc[i][j] = (f32x4){0.f, 0.f, 0.f, 0.f};

  int l15 = lane & 15, lg = lane >> 4, lx = lane & 7;
  int ch0 = (lg ^ lx) * 8;
  int ch1 = ((4 + lg) ^ lx) * 8;
  int aoff = wm * 6144 + l15 * 64;
  int boff = 12288 + wn * 4096 + l15 * 64;

#pragma unroll 1
  for (int jj = 0; jj < 24; jj++) {
    bool last = (jj == 23);
    const unsigned short* aV1 = gA + (2 * jj + 1) * 64;
    const unsigned short* aT2 = gA + (2 * jj + 2) * 64;
    const unsigned short* aT3 = gA + (2 * jj + 3) * 64;
    const unsigned short* bT2 = gB + (2 * jj + 2) * 64;
    const unsigned short* bT3 = gB + (2 * jj + 3) * 64;
    {  // ---- stage 0 (K-tile 2jj) ----
      short8 bf[4][2];
      {  // p0
        A_READS(0, 0); RDB(0);
        G2(aV1, 64, 28672 + 4096); G2(aV1, 128, 28672 + 8192);
        LGK8; ENTRY_BAR; MFMA16(0); CLOSE_BAR;
      }
      {  // p1
        A_READS(1, 0);
        if (!last) { G2(bT2, 0, 12288); G2(bT2, 64, 16384); }
        ENTRY_BAR; MFMA16(1); CLOSE_BAR;
      }
      {  // p2 (+ stage-switch wait)
        A_READS(2, 0);
        if (!last) { G2(bT2, 128, 20480); G2(bT2, 192, 24576); G2(aT2, 0, 0); }
        ENTRY_BAR; MFMA16(2);
        if (last) asm volatile("s_waitcnt vmcnt(0)" ::: "memory");
        else      asm volatile("s_waitcnt vmcnt(5)" ::: "memory");
        CLOSE_BAR;
      }
    }
    {  // ---- stage 1 (K-tile 2jj+1) ----
      short8 bf[4][2];
      {  // p3
        A_READS(0, 28672); RDB(28672);
        if (!last) { G2(aT2, 64, 4096); G2(aT2, 128, 8192); }
        LGK8; ENTRY_BAR; MFMA16(0); CLOSE_BAR;
      }
      {  // p4
        A_READS(1, 28672);
        if (!last) { G2(bT3, 0, 28672 + 12288); G2(bT3, 64, 28672 + 16384); }
        ENTRY_BAR; MFMA16(1); CLOSE_BAR;
      }
      {  // p5 (+ stage-switch wait)
        A_READS(2, 28672);
        if (!last) { G2(bT3, 128, 28672 + 20480); G2(bT3, 192, 28672 + 24576); G2(aT3, 0, 28672 + 0); }
        ENTRY_BAR; MFMA16(2);
        if (!last) asm volatile("s_waitcnt vmcnt(5)" ::: "memory");
        CLOSE_BAR;
      }
    }
  }
#undef G2

  int db0 = M0 + wm * 96 + lg * 4;
  int sb0 = N0 + wn * 64 + l15;
  float* yo = y + (size_t)pair * SS * DDIM;
#pragma unroll
  for (int j = 0; j < 4; j++) {
    int s = sb0 + j * 16;
#pragma unroll
    for (int i = 0; i < 6; i++)
      *(f32x4*)&yo[(size_t)s * DDIM + db0 + i * 16] = acc[i][j];
  }
}

// ---------------- LayerNorm + residual ----------------
__global__ void ln_kernel(const float* __restrict__ x,
                          const float* __restrict__ y,
                          const float* __restrict__ b2,
                          const int* __restrict__ topi,
                          const float* __restrict__ topv,
                          const float* __restrict__ gamma,
                          const float* __restrict__ beta,
                          float* __restrict__ out) {
  int wave = threadIdx.x >> 6, lane = threadIdx.x & 63;
  int row = blockIdx.x * 4 + wave;
  int b = row >> 10, s = row & 1023;
  int e0 = topi[b * 2], e1 = topi[b * 2 + 1];
  float tv0 = topv[b * 2], tv1 = topv[b * 2 + 1];
  const float* y0r = y + ((size_t)(b * 2) * SS + s) * DDIM;
  const float* y1r = y + ((size_t)(b * 2 + 1) * SS + s) * DDIM;
  const float* xr = x + (size_t)row * DDIM;
  float v[12];
  float sm = 0.f, s2 = 0.f;
#pragma unroll
  for (int i = 0; i < 12; i++) {
    int d = i * 64 + lane;
    float m = y0r[d] + y1r[d] + tv0 * b2[e0 * DDIM + d] + tv1 * b2[e1 * DDIM + d];
    v[i] = m; sm += m; s2 += m * m;
  }
#pragma unroll
  for (int o = 32; o > 0; o >>= 1) { sm += __shfl_xor(sm, o); s2 += __shfl_xor(s2, o); }
  float mu = sm * (1.f / DDIM);
  float var = s2 * (1.f / DDIM) - mu * mu;
  float rs = rsqrtf(var + 1e-5f);
  float* orow = out + (size_t)row * DDIM;
#pragma unroll
  for (int i = 0; i < 12; i++) {
    int d = i * 64 + lane;
    orow[d] = xr[d] + (v[i] - mu) * rs * gamma[d] + beta[d];
  }
}

extern "C" void kernel_launch(void* const* d_in, const int* in_sizes, int n_in,
                              void* d_out, int out_size, void* d_ws, size_t ws_size,
                              hipStream_t stream) {
  const float* x     = (const float*)d_in[0];
  const float* text  = (const float*)d_in[1];
  const float* W1    = (const float*)d_in[2];
  const float* b1    = (const float*)d_in[3];
  const float* W2    = (const float*)d_in[4];
  const float* b2    = (const float*)d_in[5];
  const float* rw    = (const float*)d_in[6];
  const float* rb    = (const float*)d_in[7];
  const float* gamma = (const float*)d_in[8];
  const float* beta  = (const float*)d_in[9];
  float* out   = (float*)d_out;
  float* probs = out + (size_t)BB * SS * DDIM;

  char* ws = (char*)d_ws;
  int*   topi   = (int*)ws;
  float* topv   = (float*)(ws + 256);
  float* pooled = (float*)(ws + 512);
  size_t off = 25088;
  unsigned short* xb  = (unsigned short*)(ws + off);                 // 12.58 MB
  unsigned short* w1t = (unsigned short*)(ws + off + 12582912);      // 37.75 MB
  unsigned short* w2t = w1t + (size_t)EE * DDIM * FFF;               // 37.75 MB
  unsigned short* hbuf = w2t + (size_t)EE * DDIM * FFF;              // 100.66 MB
  float* yb = (float*)(ws + off);                                    // aliases xb+w1t

  prep_kernel<<<12480, 256, 0, stream>>>(W1, W2, x, w1t, w2t, xb, pooled);
  router_kernel<<<1, 1024, 0, stream>>>(pooled, text, rw, rb, probs, topi, topv);
  gemm1_pipe<<<256, 512, 0, stream>>>(w1t, xb, b1, topi, topv, hbuf);
  gemm2_pipe<<<256, 512, 0, stream>>>(w2t, hbuf, topi, yb);
  ln_kernel<<<(BB * SS) / 4, 256, 0, stream>>>(x, yb, b2, topi, topv, gamma, beta, out);
}